// Round 6
// baseline (119.166 us; speedup 1.0000x reference)
//
#include <hip/hip_runtime.h>
#include <hip/hip_bf16.h>
#include <math.h>

typedef __hip_bfloat16 bf16;
typedef __bf16 bf16x8 __attribute__((ext_vector_type(8)));
typedef float f32x4 __attribute__((ext_vector_type(4)));
typedef unsigned short u16x8 __attribute__((ext_vector_type(8)));

#define B_SZ   4
#define T_SEQ  2048
#define D_IN   1024
#define D_QKV  64
#define BT     (B_SZ * T_SEQ)   // 8192 rows
#define PSTR   72               // attn p-tile LDS row stride (+8 pad, 16B rows)

// async global->LDS DMA, 16B per lane; LDS dest = uniform base + lane*16
#define GLD_LDS(gp, lp) __builtin_amdgcn_global_load_lds(                     \
    (const __attribute__((address_space(1))) void*)(gp),                      \
    (__attribute__((address_space(3))) void*)(lp), 16, 0, 0)

// counted waits (T4): never vmcnt(0) in steady state. In-order vmcnt retire
// makes vmcnt(N) == "all but the N newest loads have landed".
#define VMCNT0 asm volatile("s_waitcnt vmcnt(0)" ::: "memory")
#define VMCNT1 asm volatile("s_waitcnt vmcnt(1)" ::: "memory")
#define VMCNT2 asm volatile("s_waitcnt vmcnt(2)" ::: "memory")
#define VMCNT4 asm volatile("s_waitcnt vmcnt(4)" ::: "memory")

// ---------------------------------------------------------------------------
// Kernel 0: W transpose/convert via LDS, coalesced. Wt[n][k] bf16, n=0..191.
// (verbatim from R4, verified)
// ---------------------------------------------------------------------------
__global__ __launch_bounds__(256) void wt_prep(
    const float* __restrict__ Wq, const float* __restrict__ Wk,
    const float* __restrict__ Wv, bf16* __restrict__ wt)
{
    __shared__ float ws[64 * 65];
    const int bx = blockIdx.x;
    const int m  = bx >> 4;
    const int k0 = (bx & 15) << 6;
    const float* W = (m == 0) ? Wq : (m == 1) ? Wk : Wv;
    const int tid = threadIdx.x;
    #pragma unroll
    for (int i = 0; i < 16; ++i) {
        const int idx = i * 256 + tid;
        const int kk = idx >> 6, nn = idx & 63;
        ws[kk * 65 + nn] = W[(size_t)(k0 + kk) * D_QKV + nn];
    }
    __syncthreads();
    const int n = tid >> 2, kq = (tid & 3) << 4;
    bf16 tmp[16];
    #pragma unroll
    for (int j = 0; j < 16; ++j)
        tmp[j] = __float2bfloat16(ws[(kq + j) * 65 + n]);
    uint4* dst = (uint4*)(wt + (size_t)(m * 64 + n) * D_IN + k0 + kq);
    dst[0] = ((uint4*)tmp)[0];
    dst[1] = ((uint4*)tmp)[1];
}

// ---------------------------------------------------------------------------
// Kernel A v4 (verbatim from R4, verified): QKV projection GEMM, 16-row x
// 192-col tiles, 512 blocks, counted-vmcnt pipeline: A 4-buffer/3-ahead,
// B 2-buffer/1-ahead.
// ---------------------------------------------------------------------------
__global__ __launch_bounds__(256) void qkv_proj_mfma(
    const float* __restrict__ x, const bf16* __restrict__ wt,
    bf16* __restrict__ qb, bf16* __restrict__ kb, bf16* __restrict__ vt)
{
    __shared__ uint4 As[4][256];     // 4 x 4 KB  (16 rows x 64 k fp32)
    __shared__ uint4 Bs[2][1536];    // 2 x 24 KB (192 n x 64 k bf16)

    const int tid  = threadIdx.x;
    const int wave = tid >> 6;
    const int lane = tid & 63;
    const int col  = lane & 15;
    const int quad = lane >> 4;
    const int m0   = blockIdx.x * 16;

    f32x4 acc[3];
    #pragma unroll
    for (int i = 0; i < 3; ++i) acc[i] = (f32x4){0.f, 0.f, 0.f, 0.f};

    auto stage_A = [&](int it, int buf) {        // 1 load per wave
        const int k0 = it * 64;
        const int s = wave;
        const int c = s * 64 + lane;
        const int r = c >> 4;
        const int ccl = ((c & 15) - r) & 15;
        const float* g = x + (size_t)(m0 + r) * D_IN + k0 + ccl * 4;
        GLD_LDS(g, &As[buf][s * 64]);
    };
    auto stage_B = [&](int it, int buf) {        // 6 loads per wave
        const int k0 = it * 64;
        #pragma unroll
        for (int j = 0; j < 6; ++j) {
            const int bs = wave + j * 4;
            const int c = bs * 64 + lane;
            const int n = c >> 3;
            const int ccl = ((c & 7) - n) & 7;
            const bf16* g = wt + (size_t)n * D_IN + k0 + ccl * 8;
            GLD_LDS(g, &Bs[buf][bs * 64]);
        }
    };

    stage_B(0, 0);
    stage_A(0, 0);
    stage_A(1, 1);
    stage_A(2, 2);

    const int r = col;
    #pragma unroll 1
    for (int it = 0; it < 16; ++it) {
        if (it == 0)       VMCNT2;
        else if (it < 14)  VMCNT1;
        else               VMCNT0;
        __builtin_amdgcn_s_barrier();

        if (it + 1 < 16) stage_B(it + 1, (it + 1) & 1);
        if (it + 3 < 16) stage_A(it + 3, (it + 3) & 3);

        const float4* Ac = (const float4*)As[it & 3];
        const uint4*  Bc = Bs[it & 1];
        #pragma unroll
        for (int s = 0; s < 2; ++s) {
            const int ca = s * 8 + quad * 2;
            const float4 a0 = Ac[r * 16 + ((ca + r) & 15)];
            const float4 a1 = Ac[r * 16 + ((ca + 1 + r) & 15)];
            const bf16x8 af = (bf16x8){(__bf16)a0.x, (__bf16)a0.y, (__bf16)a0.z, (__bf16)a0.w,
                                       (__bf16)a1.x, (__bf16)a1.y, (__bf16)a1.z, (__bf16)a1.w};
            #pragma unroll
            for (int i = 0; i < 3; ++i) {
                const int n = wave * 48 + i * 16 + col;
                const bf16x8 bfr = __builtin_bit_cast(bf16x8,
                    Bc[n * 8 + ((s * 4 + quad + n) & 7)]);
                acc[i] = __builtin_amdgcn_mfma_f32_16x16x32_bf16(af, bfr, acc[i], 0, 0, 0);
            }
        }
    }

    // epilogue: q/k row-major bf16, v transposed bf16
    const int bb = m0 >> 11;
    const int tl = m0 & (T_SEQ - 1);
    #pragma unroll
    for (int i = 0; i < 3; ++i) {
        const int n = wave * 48 + i * 16 + col;
        #pragma unroll
        for (int rr = 0; rr < 4; ++rr) {
            const int row = m0 + quad * 4 + rr;
            const bf16 vq = __float2bfloat16(acc[i][rr]);
            if (n < 64)       qb[(size_t)row * D_QKV + n] = vq;
            else if (n < 128) kb[(size_t)row * D_QKV + (n - 64)] = vq;
            else              vt[(size_t)bb * D_QKV * T_SEQ + (size_t)(n - 128) * T_SEQ
                                 + (tl + quad * 4 + rr)] = vq;
        }
    }
}

// ---------------------------------------------------------------------------
// Kernel B v6: flash attention with DIRECT output, minimal diff from the
// VERIFIED v4 loop. One block per (batch, 64-row q-tile) = 128 blocks; the
// block walks ALL chunks 0..t (no segments, no quarters), so it owns its
// rows' complete numerator+denominator -> divide in-kernel, write out.
// Op/lp partials and the combine kernel are deleted (saves the 34.6 MB
// partial round-trip + one dispatch). 3-buffer / 2-ahead staging, counted
// vmcnt: 4 loads/wave/stage -> steady VMCNT4, tail VMCNT0.
// ---------------------------------------------------------------------------
__global__ __launch_bounds__(256) void attn_kernel(
    const bf16* __restrict__ qb, const bf16* __restrict__ kb,
    const bf16* __restrict__ vt, float* __restrict__ out)
{
    __shared__ uint4 Ks[3][512];                 // 3 x 8 KB
    __shared__ uint4 Vs[3][512];                 // 3 x 8 KB
    __shared__ unsigned short plds[4 * 16 * PSTR];

    const int tid  = threadIdx.x;
    const int wave = tid >> 6;
    const int lane = tid & 63;
    const int col  = lane & 15;
    const int quad = lane >> 4;
    const int bx   = blockIdx.x;
    const int b    = bx >> 5;                    // batch
    const int t    = bx & 31;                    // q tile within batch
    const int nch  = t + 1;                      // causal chunk count

    const bf16* kbp = kb + (size_t)b * T_SEQ * D_QKV;
    const bf16* vtp = vt + (size_t)b * D_QKV * T_SEQ;
    const uint4* q4 = (const uint4*)(qb + (size_t)b * T_SEQ * D_QKV);

    // Q A-fragments for this wave's 16 rows (loaded once; retires before
    // the first VMCNT4 check-point by in-order vmcnt retirement)
    const int qrow = t * 64 + wave * 16 + col;
    const bf16x8 aq0 = __builtin_bit_cast(bf16x8, q4[qrow * 8 + quad]);
    const bf16x8 aq1 = __builtin_bit_cast(bf16x8, q4[qrow * 8 + 4 + quad]);

    f32x4 o[4];
    float ls[4];
    #pragma unroll
    for (int dt = 0; dt < 4; ++dt) o[dt] = (f32x4){0.f, 0.f, 0.f, 0.f};
    #pragma unroll
    for (int rr = 0; rr < 4; ++rr) ls[rr] = 0.f;

    unsigned short* pl = plds + wave * 16 * PSTR;
    const u16x8* p8 = (const u16x8*)pl;

    auto stage = [&](int c, int buf) {           // 4 loads per wave (verbatim v4)
        const int kb0 = c * 64;
        #pragma unroll
        for (int j = 0; j < 4; ++j) {
            const int s = wave + j * 4;
            if (s < 8) {                         // K: 8 slots
                const int ch = s * 64 + lane;
                const int key = ch >> 3;
                const int ccl = ((ch & 7) - key) & 7;
                const bf16* g = kbp + (size_t)(kb0 + key) * D_QKV + ccl * 8;
                GLD_LDS(g, &Ks[buf][s * 64]);
            } else {                             // V: 8 slots
                const int vs = s - 8;
                const int ch = vs * 64 + lane;
                const int d = ch >> 3;
                const int ccl = ((ch & 7) - d) & 7;
                const bf16* g = vtp + (size_t)d * T_SEQ + kb0 + ccl * 8;
                GLD_LDS(g, &Vs[buf][vs * 64]);
            }
        }
    };

    // prologue: stage chunks 0,1 into bufs 0,1
    stage(0, 0);
    if (nch > 1) stage(1, 1);

    #pragma unroll 1
    for (int c = 0; c < nch; ++c) {
        // counted wait: stage(c) landed; stage(c+1)'s 4 loads may fly on.
        if (c + 1 < nch) VMCNT4; else VMCNT0;
        __builtin_amdgcn_s_barrier();
        if (c + 2 < nch) stage(c + 2, (c + 2) % 3);

        const uint4* Kc = Ks[c % 3];
        const uint4* Vc = Vs[c % 3];

        // QK^T from LDS K
        f32x4 sc4[4];
        #pragma unroll
        for (int nt2 = 0; nt2 < 4; ++nt2) {
            const int kp = nt2 * 16 + col;
            const bf16x8 bk0 = __builtin_bit_cast(bf16x8, Kc[kp * 8 + ((quad + kp) & 7)]);
            const bf16x8 bk1 = __builtin_bit_cast(bf16x8, Kc[kp * 8 + ((4 + quad + kp) & 7)]);
            sc4[nt2] = (f32x4){0.f, 0.f, 0.f, 0.f};
            sc4[nt2] = __builtin_amdgcn_mfma_f32_16x16x32_bf16(aq0, bk0, sc4[nt2], 0, 0, 0);
            sc4[nt2] = __builtin_amdgcn_mfma_f32_16x16x32_bf16(aq1, bk1, sc4[nt2], 0, 0, 0);
        }

        // causal mask (diagonal chunk only)
        if (c == t) {
            #pragma unroll
            for (int nt2 = 0; nt2 < 4; ++nt2) {
                const int kp = c * 64 + nt2 * 16 + col;
                #pragma unroll
                for (int rr = 0; rr < 4; ++rr)
                    if (kp > t * 64 + wave * 16 + quad * 4 + rr) sc4[nt2][rr] = -INFINITY;
            }
        }

        // P = exp(s/8) raw; per-lane l accumulation
        #pragma unroll
        for (int nt2 = 0; nt2 < 4; ++nt2) {
            #pragma unroll
            for (int rr = 0; rr < 4; ++rr) {
                const float pv = __expf(sc4[nt2][rr] * 0.125f);
                ls[rr] += pv;
                pl[(quad * 4 + rr) * PSTR + nt2 * 16 + col] =
                    __builtin_bit_cast(unsigned short, __float2bfloat16(pv));
            }
        }

        // P A-fragments (same-wave RAW via lgkmcnt)
        const bf16x8 pa0 = __builtin_bit_cast(bf16x8, p8[col * 9 + quad]);
        const bf16x8 pa1 = __builtin_bit_cast(bf16x8, p8[col * 9 + 4 + quad]);

        // O += P * V from LDS V
        #pragma unroll
        for (int dt = 0; dt < 4; ++dt) {
            const int dp = dt * 16 + col;
            const bf16x8 bv0 = __builtin_bit_cast(bf16x8, Vc[dp * 8 + ((quad + dp) & 7)]);
            const bf16x8 bv1 = __builtin_bit_cast(bf16x8, Vc[dp * 8 + ((4 + quad + dp) & 7)]);
            o[dt] = __builtin_amdgcn_mfma_f32_16x16x32_bf16(pa0, bv0, o[dt], 0, 0, 0);
            o[dt] = __builtin_amdgcn_mfma_f32_16x16x32_bf16(pa1, bv1, o[dt], 0, 0, 0);
        }
    }

    // l reduction over the 16 key-lanes (verbatim v4)
    float lr[4];
    #pragma unroll
    for (int rr = 0; rr < 4; ++rr) {
        lr[rr] = ls[rr];
        #pragma unroll
        for (int msk = 1; msk < 16; msk <<= 1)
            lr[rr] += __shfl_xor(lr[rr], msk);
    }

    // divide and store final output (replaces Op/lp partial store + combine)
    const int rowb = b * T_SEQ + t * 64 + wave * 16 + quad * 4;
    #pragma unroll
    for (int rr = 0; rr < 4; ++rr) {
        const float rden = 1.f / lr[rr];
        #pragma unroll
        for (int dt = 0; dt < 4; ++dt)
            out[(size_t)(rowb + rr) * D_QKV + dt * 16 + col] = o[dt][rr] * rden;
    }
}

// ---------------------------------------------------------------------------
extern "C" void kernel_launch(void* const* d_in, const int* in_sizes, int n_in,
                              void* d_out, int out_size, void* d_ws, size_t ws_size,
                              hipStream_t stream) {
    const float* x  = (const float*)d_in[0];
    const float* Wq = (const float*)d_in[1];
    const float* Wk = (const float*)d_in[2];
    const float* Wv = (const float*)d_in[3];
    float* out = (float*)d_out;

    char* ws = (char*)d_ws;
    bf16*  qb = (bf16*)(ws);                          // 1 MB
    bf16*  kb = (bf16*)(ws + (1u << 20));             // 1 MB
    bf16*  vt = (bf16*)(ws + (2u << 20));             // 1 MB
    bf16*  wt = (bf16*)(ws + (3u << 20));             // 384 KB

    wt_prep<<<48, 256, 0, stream>>>(Wq, Wk, Wv, wt);
    qkv_proj_mfma<<<512, 256, 0, stream>>>(x, wt, qb, kb, vt);
    attn_kernel<<<128, 256, 0, stream>>>(qb, kb, vt, out);
}

// Round 7
// 109.414 us; speedup vs baseline: 1.0891x; 1.0891x over previous
//
#include <hip/hip_runtime.h>
#include <hip/hip_bf16.h>
#include <math.h>

typedef __hip_bfloat16 bf16;
typedef __bf16 bf16x8 __attribute__((ext_vector_type(8)));
typedef float f32x4 __attribute__((ext_vector_type(4)));
typedef unsigned short u16x8 __attribute__((ext_vector_type(8)));

#define B_SZ   4
#define T_SEQ  2048
#define D_IN   1024
#define D_QKV  64
#define BT     (B_SZ * T_SEQ)   // 8192 rows
#define PSTR   72               // attn p-tile LDS row stride (+8 pad, 16B rows)
#define TOTW   2112             // total attn work items (4 batches x 528)
#define ANB    512              // attn blocks; each owns 33/8 = 4.125 items

// async global->LDS DMA, 16B per lane; LDS dest = uniform base + lane*16
#define GLD_LDS(gp, lp) __builtin_amdgcn_global_load_lds(                     \
    (const __attribute__((address_space(1))) void*)(gp),                      \
    (__attribute__((address_space(3))) void*)(lp), 16, 0, 0)

// ---------------------------------------------------------------------------
// Kernel 0: W transpose/convert via LDS, coalesced. Wt[n][k] bf16, n=0..191.
// ---------------------------------------------------------------------------
__global__ __launch_bounds__(256) void wt_prep(
    const float* __restrict__ Wq, const float* __restrict__ Wk,
    const float* __restrict__ Wv, bf16* __restrict__ wt)
{
    __shared__ float ws[64 * 65];
    const int bx = blockIdx.x;
    const int m  = bx >> 4;
    const int k0 = (bx & 15) << 6;
    const float* W = (m == 0) ? Wq : (m == 1) ? Wk : Wv;
    const int tid = threadIdx.x;
    #pragma unroll
    for (int i = 0; i < 16; ++i) {
        const int idx = i * 256 + tid;
        const int kk = idx >> 6, nn = idx & 63;
        ws[kk * 65 + nn] = W[(size_t)(k0 + kk) * D_QKV + nn];
    }
    __syncthreads();
    const int n = tid >> 2, kq = (tid & 3) << 4;
    bf16 tmp[16];
    #pragma unroll
    for (int j = 0; j < 16; ++j)
        tmp[j] = __float2bfloat16(ws[(kq + j) * 65 + n]);
    uint4* dst = (uint4*)(wt + (size_t)(m * 64 + n) * D_IN + k0 + kq);
    dst[0] = ((uint4*)tmp)[0];
    dst[1] = ((uint4*)tmp)[1];
}

// ---------------------------------------------------------------------------
// Kernel A v3: QKV projection GEMM. 16-row x 192-col tiles, 512 blocks
// (2/CU for drain overlap) AND single x read (33.5 MB HBM). B (full 192
// cols) re-read per block from 384 KB L2-resident wt.
// LDS swizzle: A phys_ch=(ch+row)&15 (16B ch), B phys_ch=(ch+n)&7.
// ---------------------------------------------------------------------------
__global__ __launch_bounds__(256) void qkv_proj_mfma(
    const float* __restrict__ x, const bf16* __restrict__ wt,
    bf16* __restrict__ qb, bf16* __restrict__ kb, bf16* __restrict__ vt)
{
    __shared__ uint4 As[2][256];     // 2 x 4 KB  (16 rows x 64 k fp32)
    __shared__ uint4 Bs[2][1536];    // 2 x 24 KB (192 n x 64 k bf16)

    const int tid  = threadIdx.x;
    const int wave = tid >> 6;
    const int lane = tid & 63;
    const int col  = lane & 15;
    const int quad = lane >> 4;
    const int m0   = blockIdx.x * 16;

    f32x4 acc[3];
    #pragma unroll
    for (int i = 0; i < 3; ++i) acc[i] = (f32x4){0.f, 0.f, 0.f, 0.f};

    auto stage = [&](int it, int buf) {
        const int k0 = it * 64;
        #pragma unroll
        for (int j = 0; j < 7; ++j) {
            const int s = wave + j * 4;          // 0..27, wave-uniform
            if (s < 4) {                         // A: 4 slots x 1KB (16 rows fp32)
                const int c = s * 64 + lane;     // float4 units, [0,256)
                const int r = c >> 4;            // row 0..15
                const int ccl = ((c & 15) - r) & 15;
                const float* g = x + (size_t)(m0 + r) * D_IN + k0 + ccl * 4;
                GLD_LDS(g, &As[buf][s * 64]);
            } else {                             // B: 24 slots x 1KB (192 n bf16)
                const int bs = s - 4;
                const int c = bs * 64 + lane;    // [0,1536)
                const int n = c >> 3;            // 0..191
                const int ccl = ((c & 7) - n) & 7;
                const bf16* g = wt + (size_t)n * D_IN + k0 + ccl * 8;
                GLD_LDS(g, &Bs[buf][bs * 64]);
            }
        }
    };

    stage(0, 0);
    const int r = col;                           // A row (all waves share rows)
    #pragma unroll 1
    for (int it = 0; it < 16; ++it) {
        __syncthreads();                         // staging(it) done, buf free
        if (it + 1 < 16) stage(it + 1, (it + 1) & 1);   // DMA overlaps compute
        const float4* Ac = (const float4*)As[it & 1];
        const uint4*  Bc = Bs[it & 1];
        #pragma unroll
        for (int s = 0; s < 2; ++s) {
            const int ca = s * 8 + quad * 2;
            const float4 a0 = Ac[r * 16 + ((ca + r) & 15)];
            const float4 a1 = Ac[r * 16 + ((ca + 1 + r) & 15)];
            const bf16x8 af = (bf16x8){(__bf16)a0.x, (__bf16)a0.y, (__bf16)a0.z, (__bf16)a0.w,
                                       (__bf16)a1.x, (__bf16)a1.y, (__bf16)a1.z, (__bf16)a1.w};
            #pragma unroll
            for (int i = 0; i < 3; ++i) {
                const int n = wave * 48 + i * 16 + col;
                const bf16x8 bfr = __builtin_bit_cast(bf16x8,
                    Bc[n * 8 + ((s * 4 + quad + n) & 7)]);
                acc[i] = __builtin_amdgcn_mfma_f32_16x16x32_bf16(af, bfr, acc[i], 0, 0, 0);
            }
        }
    }

    // epilogue: q/k row-major bf16, v transposed bf16
    const int bb = m0 >> 11;
    const int tl = m0 & (T_SEQ - 1);
    #pragma unroll
    for (int i = 0; i < 3; ++i) {
        const int n = wave * 48 + i * 16 + col;
        #pragma unroll
        for (int rr = 0; rr < 4; ++rr) {
            const int row = m0 + quad * 4 + rr;
            const bf16 vq = __float2bfloat16(acc[i][rr]);
            if (n < 64)       qb[(size_t)row * D_QKV + n] = vq;
            else if (n < 128) kb[(size_t)row * D_QKV + (n - 64)] = vq;
            else              vt[(size_t)bb * D_QKV * T_SEQ + (size_t)(n - 128) * T_SEQ
                                 + (tl + quad * 4 + rr)] = vq;
        }
    }
}

// ---------------------------------------------------------------------------
// Kernel B v3: balanced flash attention. 2112 equal-cost work items
// (batch b, tile t, chunk c) enumerated triangularly; block bx owns the
// contiguous range [(bx*33)>>3, ((bx+1)*33)>>3) -- 4 or 5 items. Partials
// written per (block x tile) segment at slot = segment's first work-item
// index; combine re-derives segments.
// ---------------------------------------------------------------------------
__global__ __launch_bounds__(256) void attn_kernel(
    const bf16* __restrict__ qb, const bf16* __restrict__ kb,
    const bf16* __restrict__ vt, float* __restrict__ Op, float* __restrict__ lp)
{
    __shared__ uint4 Ks[2][512];                 // 2 x 8 KB
    __shared__ uint4 Vs[2][512];                 // 2 x 8 KB
    __shared__ unsigned short plds[4 * 16 * PSTR];

    const int tid  = threadIdx.x;
    const int wave = tid >> 6;
    const int lane = tid & 63;
    const int col  = lane & 15;
    const int quad = lane >> 4;
    const int bx   = blockIdx.x;

    const int lo = (bx * 33) >> 3;
    const int hi = ((bx + 1) * 33) >> 3;
    const int items = hi - lo;                   // 4 or 5

    // decode first work item lo -> (b, t, c)
    int b = lo / 528;
    int rres = lo - b * 528;
    int t = (int)((sqrtf(8.f * (float)rres + 1.f) - 1.f) * 0.5f);
    while ((t + 1) * (t + 2) / 2 <= rres) ++t;
    while (t * (t + 1) / 2 > rres) --t;
    int c = rres - t * (t + 1) / 2;

    unsigned short* pl = plds + wave * 16 * PSTR;
    const u16x8* p8 = (const u16x8*)pl;

    auto stage = [&](int sb, int sc, int buf) {
        const bf16* kbp = kb + (size_t)sb * T_SEQ * D_QKV;
        const bf16* vtp = vt + (size_t)sb * D_QKV * T_SEQ;
        const int kb0 = sc * 64;
        #pragma unroll
        for (int j = 0; j < 4; ++j) {
            const int s = wave + j * 4;
            if (s < 8) {                         // K: 8 slots
                const int ch = s * 64 + lane;
                const int key = ch >> 3;
                const int ccl = ((ch & 7) - key) & 7;
                const bf16* g = kbp + (size_t)(kb0 + key) * D_QKV + ccl * 8;
                GLD_LDS(g, &Ks[buf][s * 64]);
            } else {                             // V: 8 slots
                const int vs = s - 8;
                const int ch = vs * 64 + lane;
                const int d = ch >> 3;
                const int ccl = ((ch & 7) - d) & 7;
                const bf16* g = vtp + (size_t)d * T_SEQ + kb0 + ccl * 8;
                GLD_LDS(g, &Vs[buf][vs * 64]);
            }
        }
    };

    stage(b, c, 0);

    bf16x8 aq0, aq1;
    f32x4 o[4];
    float ls[4];
    int segw = lo;

    #pragma unroll 1
    for (int i = 0; i < items; ++i) {
        // segment start: (re)load Q fragments, zero accumulators
        if (i == 0 || c == 0) {
            const uint4* q4 = (const uint4*)(qb + (size_t)b * T_SEQ * D_QKV);
            const int qrow = t * 64 + wave * 16 + col;
            aq0 = __builtin_bit_cast(bf16x8, q4[qrow * 8 + quad]);
            aq1 = __builtin_bit_cast(bf16x8, q4[qrow * 8 + 4 + quad]);
            #pragma unroll
            for (int dt = 0; dt < 4; ++dt) o[dt] = (f32x4){0.f, 0.f, 0.f, 0.f};
            #pragma unroll
            for (int rr = 0; rr < 4; ++rr) ls[rr] = 0.f;
            segw = lo + i;
        }

        // next item coords (for prefetch)
        int nb = b, nt = t, nc = c + 1;
        if (nc > t) { nc = 0; ++nt; if (nt == 32) { nt = 0; ++nb; } }

        __syncthreads();                         // stage(i) complete
        if (i + 1 < items) stage(nb, nc, (i + 1) & 1);
        const uint4* Kc = Ks[i & 1];
        const uint4* Vc = Vs[i & 1];

        // QK^T from LDS K
        f32x4 sc4[4];
        #pragma unroll
        for (int nt2 = 0; nt2 < 4; ++nt2) {
            const int kp = nt2 * 16 + col;
            const bf16x8 bk0 = __builtin_bit_cast(bf16x8, Kc[kp * 8 + ((quad + kp) & 7)]);
            const bf16x8 bk1 = __builtin_bit_cast(bf16x8, Kc[kp * 8 + ((4 + quad + kp) & 7)]);
            sc4[nt2] = (f32x4){0.f, 0.f, 0.f, 0.f};
            sc4[nt2] = __builtin_amdgcn_mfma_f32_16x16x32_bf16(aq0, bk0, sc4[nt2], 0, 0, 0);
            sc4[nt2] = __builtin_amdgcn_mfma_f32_16x16x32_bf16(aq1, bk1, sc4[nt2], 0, 0, 0);
        }

        // causal mask (diagonal chunk only)
        if (c == t) {
            #pragma unroll
            for (int nt2 = 0; nt2 < 4; ++nt2) {
                const int kp = c * 64 + nt2 * 16 + col;
                #pragma unroll
                for (int rr = 0; rr < 4; ++rr)
                    if (kp > t * 64 + wave * 16 + quad * 4 + rr) sc4[nt2][rr] = -INFINITY;
            }
        }

        // P = exp(s/8) raw; per-lane l accumulation
        #pragma unroll
        for (int nt2 = 0; nt2 < 4; ++nt2) {
            #pragma unroll
            for (int rr = 0; rr < 4; ++rr) {
                const float pv = __expf(sc4[nt2][rr] * 0.125f);
                ls[rr] += pv;
                pl[(quad * 4 + rr) * PSTR + nt2 * 16 + col] =
                    __builtin_bit_cast(unsigned short, __float2bfloat16(pv));
            }
        }

        // P A-fragments (same-wave RAW via lgkmcnt)
        const bf16x8 pa0 = __builtin_bit_cast(bf16x8, p8[col * 9 + quad]);
        const bf16x8 pa1 = __builtin_bit_cast(bf16x8, p8[col * 9 + 4 + quad]);

        // O += P * V from LDS V
        #pragma unroll
        for (int dt = 0; dt < 4; ++dt) {
            const int dp = dt * 16 + col;
            const bf16x8 bv0 = __builtin_bit_cast(bf16x8, Vc[dp * 8 + ((quad + dp) & 7)]);
            const bf16x8 bv1 = __builtin_bit_cast(bf16x8, Vc[dp * 8 + ((4 + quad + dp) & 7)]);
            o[dt] = __builtin_amdgcn_mfma_f32_16x16x32_bf16(pa0, bv0, o[dt], 0, 0, 0);
            o[dt] = __builtin_amdgcn_mfma_f32_16x16x32_bf16(pa1, bv1, o[dt], 0, 0, 0);
        }

        // segment end: reduce l, write partials at slot segw
        if (c == t || i == items - 1) {
            float lr[4];
            #pragma unroll
            for (int rr = 0; rr < 4; ++rr) {
                lr[rr] = ls[rr];
                #pragma unroll
                for (int msk = 1; msk < 16; msk <<= 1)
                    lr[rr] += __shfl_xor(lr[rr], msk);
            }
            const int pbase = segw * 64 + wave * 16;
            #pragma unroll
            for (int dt = 0; dt < 4; ++dt)
                #pragma unroll
                for (int rr = 0; rr < 4; ++rr)
                    Op[(size_t)(pbase + quad * 4 + rr) * D_QKV + dt * 16 + col] = o[dt][rr];
            if (col == 0) {
                #pragma unroll
                for (int rr = 0; rr < 4; ++rr)
                    lp[pbase + quad * 4 + rr] = lr[rr];
            }
        }

        b = nb; t = nt; c = nc;
    }
}

// ---------------------------------------------------------------------------
// Kernel C v2: combine variable per-tile segments: out = sum(O_seg)/sum(l_seg).
// Segment starts re-derived arithmetically: owner(w) = (8w+7)/33; a segment
// starts at chunk c=0 or where the owning block changes.
// ---------------------------------------------------------------------------
__global__ __launch_bounds__(256) void combine_attn(
    const float* __restrict__ Op, const float* __restrict__ lp,
    float* __restrict__ out)
{
    const int idx = blockIdx.x * 256 + threadIdx.x;   // 524288 = 8192*64
    const int qg = idx >> 6, d = idx & 63;
    const int g = qg >> 6, qq = qg & 63;              // global tile, local row
    const int b = g >> 5, t = g & 31;
    const int W0 = b * 528 + t * (t + 1) / 2;
    float s = 0.f, l = 0.f;
    int prevown = (8 * (W0 - 1) + 7) / 33;            // owner before tile start
    #pragma unroll 1
    for (int c = 0; c <= t; ++c) {
        const int w = W0 + c;
        const int own = (8 * w + 7) / 33;
        if (c == 0 || own != prevown) {
            s += Op[(size_t)(w * 64 + qq) * D_QKV + d];
            l += lp[w * 64 + qq];
        }
        prevown = own;
    }
    out[(size_t)qg * D_QKV + d] = s / l;
}

// ---------------------------------------------------------------------------
extern "C" void kernel_launch(void* const* d_in, const int* in_sizes, int n_in,
                              void* d_out, int out_size, void* d_ws, size_t ws_size,
                              hipStream_t stream) {
    const float* x  = (const float*)d_in[0];
    const float* Wq = (const float*)d_in[1];
    const float* Wk = (const float*)d_in[2];
    const float* Wv = (const float*)d_in[3];
    float* out = (float*)d_out;

    char* ws = (char*)d_ws;
    bf16*  qb = (bf16*)(ws);                          // 1 MB
    bf16*  kb = (bf16*)(ws + (1u << 20));             // 1 MB
    bf16*  vt = (bf16*)(ws + (2u << 20));             // 1 MB
    bf16*  wt = (bf16*)(ws + (3u << 20));             // 384 KB
    float* Op = (float*)(ws + (4u << 20));            // 2112*64*64*4 = 34.6 MB
    float* lp = (float*)(ws + (40u << 20));           // 2112*64*4 = 540 KB

    wt_prep<<<48, 256, 0, stream>>>(Wq, Wk, Wv, wt);
    qkv_proj_mfma<<<512, 256, 0, stream>>>(x, wt, qb, kb, vt);
    attn_kernel<<<ANB, 256, 0, stream>>>(qb, kb, vt, Op, lp);
    combine_attn<<<2048, 256, 0, stream>>>(Op, lp, out);
}